// Round 4
// baseline (381.277 us; speedup 1.0000x reference)
//
#include <hip/hip_runtime.h>
#include <hip/hip_bf16.h>

#define N_ATOMS 30000
#define M_NBR   12
#define A_DIM   256
#define B_DIM   128

typedef __bf16 bf16x8 __attribute__((ext_vector_type(8)));
typedef float  f32x4  __attribute__((ext_vector_type(4)));

__device__ __forceinline__ unsigned short f2bf(float f) {
    union { float f; unsigned u; } v; v.f = f;
    unsigned r = v.u + 0x7fffu + ((v.u >> 16) & 1u);
    return (unsigned short)(r >> 16);
}
__device__ __forceinline__ float bf2f(unsigned short u) {
    union { unsigned u; float f; } v; v.u = ((unsigned)u) << 16;
    return v.f;
}

// packed per-row address for z-column c (0..511):
// layout [band:8][l15:16][slot:4]; band = (c&255)>>5, slot = bit4(c&255) + 2*(c>=256).
// Consumer lane (wc,l15) reads its 4 values (2 gate + 2 core) as ONE 8B uint2.
__device__ __forceinline__ int packAddr8(int c) {
    int cc = c & 255;
    int slot = ((cc >> 4) & 1) + ((c >> 8) << 1);
    return (cc >> 5) * 64 + (cc & 15) * 4 + slot;
}

// ---------------- Kernel 0: pack fc_w into bf16 fragment-order tables ----------
__global__ void pack_weights(const float* __restrict__ fc_w,
                             unsigned short* __restrict__ Wp1,
                             unsigned short* __restrict__ Wp3) {
    int idx = blockIdx.x * 256 + threadIdx.x;
    const int n1 = 32 * 1024 * 8;
    if (idx < n1) {
        int j = idx & 7, n = (idx >> 3) & 1023, g = idx >> 13;
        float v = (n < 512) ? fc_w[n * 640 + g * 8 + j]
                            : fc_w[(n - 512) * 640 + 256 + g * 8 + j];
        Wp1[idx] = f2bf(v);
    } else {
        int k = idx - n1;
        if (k < 16 * 512 * 8) {
            int j = k & 7, n = (k >> 3) & 511, g = k >> 12;
            Wp3[k] = f2bf(fc_w[n * 640 + 512 + g * 8 + j]);
        }
    }
}

// ---------------- Kernel 1: P1 = W1*atom + b, P2 = W2*atom, stored PACKED (bf16) ---
// P row (1024 ushorts): [0:512) = P1 packed (packAddr8), [512:1024) = P2 packed.
__global__ __launch_bounds__(512, 2) void gemm_p(
    const float* __restrict__ atom, const float* __restrict__ fc_b,
    const unsigned short* __restrict__ Wp1, unsigned short* __restrict__ P)
{
    __shared__ unsigned short sA[128 * 256];   // 64KB, swizzled bf16 A-tile
    const int tid = threadIdx.x;
    const int r0 = blockIdx.x * 128;
    const int cb = blockIdx.y;                 // 0: W1 half (+bias), 1: W2 half

    #pragma unroll
    for (int s = 0; s < 8; ++s) {
        int G = tid + s * 512;
        int row = G >> 5, gc = G & 31;
        int grow = r0 + row;
        union { unsigned short u[8]; uint4 q; } pk;
        if (grow < N_ATOMS) {
            const float4* src = reinterpret_cast<const float4*>(atom + (size_t)grow * 256 + gc * 8);
            float4 v0 = src[0], v1 = src[1];
            pk.u[0]=f2bf(v0.x); pk.u[1]=f2bf(v0.y); pk.u[2]=f2bf(v0.z); pk.u[3]=f2bf(v0.w);
            pk.u[4]=f2bf(v1.x); pk.u[5]=f2bf(v1.y); pk.u[6]=f2bf(v1.z); pk.u[7]=f2bf(v1.w);
        } else {
            pk.q = make_uint4(0u, 0u, 0u, 0u);
        }
        *reinterpret_cast<uint4*>(&sA[row * 256 + ((gc ^ (row & 7)) << 3)]) = pk.q;
    }
    __syncthreads();

    const int lane = tid & 63, wave = tid >> 6;
    const int wr = wave >> 2, wcc = wave & 3;
    const int l15 = lane & 15, l16 = lane >> 4;

    f32x4 acc[4][8];
    #pragma unroll
    for (int mt = 0; mt < 4; ++mt)
        #pragma unroll
        for (int nt = 0; nt < 8; ++nt) acc[mt][nt] = f32x4{0.f, 0.f, 0.f, 0.f};

    #pragma unroll
    for (int ks = 0; ks < 8; ++ks) {
        bf16x8 af[4];
        #pragma unroll
        for (int mt = 0; mt < 4; ++mt) {
            int row = wr * 64 + mt * 16 + l15;
            int g = ks * 4 + l16;
            af[mt] = *reinterpret_cast<const bf16x8*>(&sA[row * 256 + ((g ^ (row & 7)) << 3)]);
        }
        bf16x8 bfr[8];
        #pragma unroll
        for (int nt = 0; nt < 8; ++nt) {
            int col = cb * 512 + wcc * 128 + nt * 16 + l15;
            bfr[nt] = *reinterpret_cast<const bf16x8*>(&Wp1[((size_t)(ks * 4 + l16) * 1024 + col) * 8]);
        }
        #pragma unroll
        for (int mt = 0; mt < 4; ++mt)
            #pragma unroll
            for (int nt = 0; nt < 8; ++nt)
                acc[mt][nt] = __builtin_amdgcn_mfma_f32_16x16x32_bf16(af[mt], bfr[nt], acc[mt][nt], 0, 0, 0);
    }

    // epilogue: paired bf16 (uint) writes into packed layout
    #pragma unroll
    for (int np = 0; np < 4; ++np) {
        int zc0 = wcc * 128 + np * 32 + l15;     // nt = 2*np ; zc1 = zc0 + 16
        float b0 = (cb == 0) ? fc_b[zc0] : 0.f;
        float b1 = (cb == 0) ? fc_b[zc0 + 16] : 0.f;
        int pa = cb * 512 + packAddr8(zc0);      // even; zc0+16 lands at pa+1
        #pragma unroll
        for (int mt = 0; mt < 4; ++mt) {
            #pragma unroll
            for (int j = 0; j < 4; ++j) {
                int row = r0 + wr * 64 + mt * 16 + l16 * 4 + j;
                if (row < N_ATOMS) {
                    unsigned lo = f2bf(acc[mt][2 * np][j] + b0);
                    unsigned hi = f2bf(acc[mt][2 * np + 1][j] + b1);
                    *reinterpret_cast<unsigned*>(&P[(size_t)row * 1024 + pa]) = lo | (hi << 16);
                }
            }
        }
    }
}

// ---------------- Kernel 2: fused bond-GEMM + gather-add + LN1 + gate*core + mean + LN2 + residual
// 512 threads = 8 waves; 4 atoms (48 rows). Wave wc owns 32 gate cols + 32 core cols.
__global__ __launch_bounds__(512, 3) void fused_conv(
    const float* __restrict__ atom, const float* __restrict__ bond,
    const int* __restrict__ nbr, const unsigned short* __restrict__ P,
    const unsigned short* __restrict__ Wp3,
    const float* __restrict__ ln1_g, const float* __restrict__ ln1_b,
    const float* __restrict__ ln2_g, const float* __restrict__ ln2_b,
    float* __restrict__ out)
{
    __shared__ unsigned short sA[48 * 128];              // 12KB bond tile (bf16, swizzled)
    __shared__ __align__(16) float sRed[2][48][8];       // 3KB LN1 per-wave partials
    __shared__ float sMuR[48], sRstd[48];                // LN1 folded stats
    __shared__ float sO[4][256];                         // 4KB per-atom sum of gate*core

    const int tid = threadIdx.x;
    const int i0 = blockIdx.x * 4;                       // 7500 blocks exact
    const int lane = tid & 63, wc = tid >> 6;
    const int l15 = lane & 15, l16 = lane >> 4;

    { float* so = &sO[0][0]; so[tid] = 0.f; so[tid + 512] = 0.f; }

    // ---- issue bond loads FIRST (oldest in vmcnt queue) ----
    float4 bv[2][2];
    #pragma unroll
    for (int s = 0; s < 2; ++s) {
        int G = tid + s * 512;
        if (G < 768) {
            int row = G >> 4, gc = G & 15;
            const float4* src = reinterpret_cast<const float4*>(bond + (size_t)(i0 * 12 + row) * 128 + gc * 8);
            bv[s][0] = src[0]; bv[s][1] = src[1];
        }
    }

    // ---- prefetch P2 gathers (12 rows), P1 (3), LN1 params: all in flight under GEMM prologue ----
    uint2 p2q[12];
    #pragma unroll
    for (int mt = 0; mt < 3; ++mt)
        #pragma unroll
        for (int j = 0; j < 4; ++j) {
            int row = mt * 16 + l16 * 4 + j;
            int nb = nbr[i0 * 12 + row];
            p2q[mt * 4 + j] = *reinterpret_cast<const uint2*>(&P[(size_t)nb * 1024 + 512 + wc * 64 + l15 * 4]);
        }
    uint2 p1q[3];
    #pragma unroll
    for (int mt = 0; mt < 3; ++mt) {
        int li = (mt * 16 + l16 * 4) / 12;               // j-quads never cross atoms
        p1q[mt] = *reinterpret_cast<const uint2*>(&P[(size_t)(i0 + li) * 1024 + wc * 64 + l15 * 4]);
    }
    float g1[2], b1[2], gC[2], bC[2];
    #pragma unroll
    for (int nt = 0; nt < 2; ++nt) {
        int a = wc * 32 + nt * 16 + l15;
        g1[nt] = ln1_g[a];       b1[nt] = ln1_b[a];
        gC[nt] = ln1_g[256 + a]; bC[nt] = ln1_b[256 + a];
    }

    // ---- convert + stage bond tile (waits only on the bond loads) ----
    #pragma unroll
    for (int s = 0; s < 2; ++s) {
        int G = tid + s * 512;
        if (G < 768) {
            int row = G >> 4, gc = G & 15;
            union { unsigned short u[8]; uint4 q; } pk;
            pk.u[0]=f2bf(bv[s][0].x); pk.u[1]=f2bf(bv[s][0].y); pk.u[2]=f2bf(bv[s][0].z); pk.u[3]=f2bf(bv[s][0].w);
            pk.u[4]=f2bf(bv[s][1].x); pk.u[5]=f2bf(bv[s][1].y); pk.u[6]=f2bf(bv[s][1].z); pk.u[7]=f2bf(bv[s][1].w);
            *reinterpret_cast<uint4*>(&sA[row * 128 + ((gc ^ (row & 7)) << 3)]) = pk.q;
        }
    }
    __syncthreads();

    // ---- GEMM: [48,128(bond)] @ Wp3, wave's cols = 32 gate (nt 0,1) + 32 core (nt 2,3) ----
    f32x4 acc[3][4];
    #pragma unroll
    for (int mt = 0; mt < 3; ++mt)
        #pragma unroll
        for (int nt = 0; nt < 4; ++nt) acc[mt][nt] = f32x4{0.f, 0.f, 0.f, 0.f};

    #pragma unroll
    for (int ks = 0; ks < 4; ++ks) {
        bf16x8 af[3];
        #pragma unroll
        for (int mt = 0; mt < 3; ++mt) {
            int row = mt * 16 + l15;
            int g = ks * 4 + l16;
            af[mt] = *reinterpret_cast<const bf16x8*>(&sA[row * 128 + ((g ^ (row & 7)) << 3)]);
        }
        bf16x8 bfr[4];
        #pragma unroll
        for (int nt = 0; nt < 4; ++nt) {
            int col = (nt < 2) ? (wc * 32 + nt * 16 + l15)
                               : (256 + wc * 32 + (nt - 2) * 16 + l15);
            bfr[nt] = *reinterpret_cast<const bf16x8*>(&Wp3[((size_t)(ks * 4 + l16) * 512 + col) * 8]);
        }
        #pragma unroll
        for (int mt = 0; mt < 3; ++mt)
            #pragma unroll
            for (int nt = 0; nt < 4; ++nt)
                acc[mt][nt] = __builtin_amdgcn_mfma_f32_16x16x32_bf16(af[mt], bfr[nt], acc[mt][nt], 0, 0, 0);
    }

    // ---- pass 1: z = acc + P1 + P2 (from prefetched regs), LN1 partial stats ----
    #pragma unroll
    for (int mt = 0; mt < 3; ++mt) {
        union { uint2 q; unsigned short u[4]; } c1; c1.q = p1q[mt];
        #pragma unroll
        for (int j = 0; j < 4; ++j) {
            const int row = mt * 16 + l16 * 4 + j;
            union { uint2 q; unsigned short u[4]; } c2; c2.q = p2q[mt * 4 + j];
            float s = 0.f, q = 0.f;
            #pragma unroll
            for (int nt = 0; nt < 4; ++nt) {
                float z = acc[mt][nt][j] + bf2f(c1.u[nt]) + bf2f(c2.u[nt]);
                acc[mt][nt][j] = z;
                s += z; q = fmaf(z, z, q);
            }
            #pragma unroll
            for (int msk = 1; msk <= 8; msk <<= 1) {
                s += __shfl_xor(s, msk, 64);
                q += __shfl_xor(q, msk, 64);
            }
            if (l15 == 0) { sRed[0][row][wc] = s; sRed[1][row][wc] = q; }
        }
    }
    __syncthreads();

    // ---- mini-reduce: 48 threads fold 8 wave-partials -> mu*rstd, rstd ----
    if (tid < 48) {
        const float4* r0p = reinterpret_cast<const float4*>(&sRed[0][tid][0]);
        const float4* r1p = reinterpret_cast<const float4*>(&sRed[1][tid][0]);
        float4 a0 = r0p[0], a1 = r0p[1], c0 = r1p[0], c1v = r1p[1];
        float s4 = a0.x + a0.y + a0.z + a0.w + a1.x + a1.y + a1.z + a1.w;
        float q4 = c0.x + c0.y + c0.z + c0.w + c1v.x + c1v.y + c1v.z + c1v.w;
        float mu = s4 * (1.f / 512.f);
        float var = q4 * (1.f / 512.f) - mu * mu;
        float rs = __builtin_amdgcn_rsqf(var + 1e-5f);
        sRstd[tid] = rs;
        sMuR[tid] = mu * rs;
    }
    __syncthreads();

    // ---- pass 2: LN1 affine, sigmoid*softplus, accumulate per-atom mean via LDS atomics ----
    #pragma unroll
    for (int mt = 0; mt < 3; ++mt) {
        const int li = (mt * 16 + l16 * 4) / 12;
        float rs[4], mr[4];
        #pragma unroll
        for (int j = 0; j < 4; ++j) {
            int row = mt * 16 + l16 * 4 + j;
            rs[j] = sRstd[row]; mr[j] = sMuR[row];
        }
        #pragma unroll
        for (int nt = 0; nt < 2; ++nt) {
            float tq = 0.f;
            #pragma unroll
            for (int j = 0; j < 4; ++j) {
                float zg = fmaf(acc[mt][nt][j], rs[j], -mr[j]);
                zg = fmaf(zg, g1[nt], b1[nt]);
                float zc = fmaf(acc[mt][nt + 2][j], rs[j], -mr[j]);
                zc = fmaf(zc, gC[nt], bC[nt]);
                float gate = __builtin_amdgcn_rcpf(1.f + __expf(-zg));
                float sp   = fmaxf(zc, 0.f) + __logf(1.f + __expf(-fabsf(zc)));
                tq += gate * sp;
            }
            atomicAdd(&sO[li][wc * 32 + nt * 16 + l15], tq);   // 3 contributors per address
        }
    }
    __syncthreads();

    // ---- mean /12 + LN2 + residual: waves 0..3, one atom each ----
    if (wc < 4) {
        const int gi = i0 + wc;
        float v[4]; float s = 0.f, q = 0.f;
        #pragma unroll
        for (int qd = 0; qd < 4; ++qd) {
            v[qd] = sO[wc][lane + qd * 64] * (1.f / 12.f);
            s += v[qd]; q = fmaf(v[qd], v[qd], q);
        }
        #pragma unroll
        for (int msk = 1; msk <= 32; msk <<= 1) {
            s += __shfl_xor(s, msk, 64);
            q += __shfl_xor(q, msk, 64);
        }
        float mu = s * (1.f / 256.f);
        float var = q * (1.f / 256.f) - mu * mu;
        float rstd = __builtin_amdgcn_rsqf(var + 1e-5f);
        #pragma unroll
        for (int qd = 0; qd < 4; ++qd) {
            int a = lane + qd * 64;
            out[(size_t)gi * 256 + a] = atom[(size_t)gi * 256 + a]
                                      + (v[qd] - mu) * rstd * ln2_g[a] + ln2_b[a];
        }
    }
}

extern "C" void kernel_launch(void* const* d_in, const int* in_sizes, int n_in,
                              void* d_out, int out_size, void* d_ws, size_t ws_size,
                              hipStream_t stream) {
    const float* atom  = (const float*)d_in[0];
    const float* bond  = (const float*)d_in[1];
    const float* fc_w  = (const float*)d_in[2];
    const float* fc_b  = (const float*)d_in[3];
    const float* ln1_g = (const float*)d_in[4];
    const float* ln1_b = (const float*)d_in[5];
    const float* ln2_g = (const float*)d_in[6];
    const float* ln2_b = (const float*)d_in[7];
    const int*   nbr   = (const int*)d_in[8];

    char* ws = (char*)d_ws;
    unsigned short* P   = (unsigned short*)ws;                          // 61,440,000 B
    unsigned short* Wp1 = (unsigned short*)(ws + 61440000);             // 524,288 B
    unsigned short* Wp3 = (unsigned short*)(ws + 61440000 + 524288);    // 131,072 B
    float* outp = (float*)d_out;

    hipLaunchKernelGGL(pack_weights, dim3(1280), dim3(256), 0, stream, fc_w, Wp1, Wp3);
    hipLaunchKernelGGL(gemm_p, dim3(235, 2), dim3(512), 0, stream, atom, fc_b, Wp1, P);
    hipLaunchKernelGGL(fused_conv, dim3(7500), dim3(512), 0, stream,
                       atom, bond, nbr, P, Wp3, ln1_g, ln1_b, ln2_g, ln2_b, outp);
}

// Round 5
// 322.329 us; speedup vs baseline: 1.1829x; 1.1829x over previous
//
#include <hip/hip_runtime.h>
#include <hip/hip_bf16.h>

#define N_ATOMS 30000
#define M_NBR   12
#define A_DIM   256
#define B_DIM   128

typedef __bf16 bf16x8 __attribute__((ext_vector_type(8)));
typedef float  f32x4  __attribute__((ext_vector_type(4)));

__device__ __forceinline__ unsigned short f2bf(float f) {
    union { float f; unsigned u; } v; v.f = f;
    unsigned r = v.u + 0x7fffu + ((v.u >> 16) & 1u);
    return (unsigned short)(r >> 16);
}
__device__ __forceinline__ float bf2f(unsigned short u) {
    union { unsigned u; float f; } v; v.u = ((unsigned)u) << 16;
    return v.f;
}

// packed per-row address for z-column c (0..511):
// layout [band:8][l15:16][slot:4]; band = (c&255)>>5, slot = bit4(c&255) + 2*(c>=256).
// Consumer lane (wc,l15) reads its 4 values (2 gate + 2 core) as ONE 8B uint2.
__device__ __forceinline__ int packAddr8(int c) {
    int cc = c & 255;
    int slot = ((cc >> 4) & 1) + ((c >> 8) << 1);
    return (cc >> 5) * 64 + (cc & 15) * 4 + slot;
}

// ---------------- Kernel 0: pack fc_w into bf16 fragment-order tables ----------
__global__ void pack_weights(const float* __restrict__ fc_w,
                             unsigned short* __restrict__ Wp1,
                             unsigned short* __restrict__ Wp3) {
    int idx = blockIdx.x * 256 + threadIdx.x;
    const int n1 = 32 * 1024 * 8;
    if (idx < n1) {
        int j = idx & 7, n = (idx >> 3) & 1023, g = idx >> 13;
        float v = (n < 512) ? fc_w[n * 640 + g * 8 + j]
                            : fc_w[(n - 512) * 640 + 256 + g * 8 + j];
        Wp1[idx] = f2bf(v);
    } else {
        int k = idx - n1;
        if (k < 16 * 512 * 8) {
            int j = k & 7, n = (k >> 3) & 511, g = k >> 12;
            Wp3[k] = f2bf(fc_w[n * 640 + 512 + g * 8 + j]);
        }
    }
}

// ---------------- Kernel 1: P1 = W1*atom + b, P2 = W2*atom, stored PACKED (bf16) ---
// P row (1024 ushorts): [0:512) = P1 packed (packAddr8), [512:1024) = P2 packed.
__global__ __launch_bounds__(512, 2) void gemm_p(
    const float* __restrict__ atom, const float* __restrict__ fc_b,
    const unsigned short* __restrict__ Wp1, unsigned short* __restrict__ P)
{
    __shared__ unsigned short sA[128 * 256];   // 64KB, swizzled bf16 A-tile
    const int tid = threadIdx.x;
    const int r0 = blockIdx.x * 128;
    const int cb = blockIdx.y;                 // 0: W1 half (+bias), 1: W2 half

    #pragma unroll
    for (int s = 0; s < 8; ++s) {
        int G = tid + s * 512;
        int row = G >> 5, gc = G & 31;
        int grow = r0 + row;
        union { unsigned short u[8]; uint4 q; } pk;
        if (grow < N_ATOMS) {
            const float4* src = reinterpret_cast<const float4*>(atom + (size_t)grow * 256 + gc * 8);
            float4 v0 = src[0], v1 = src[1];
            pk.u[0]=f2bf(v0.x); pk.u[1]=f2bf(v0.y); pk.u[2]=f2bf(v0.z); pk.u[3]=f2bf(v0.w);
            pk.u[4]=f2bf(v1.x); pk.u[5]=f2bf(v1.y); pk.u[6]=f2bf(v1.z); pk.u[7]=f2bf(v1.w);
        } else {
            pk.q = make_uint4(0u, 0u, 0u, 0u);
        }
        *reinterpret_cast<uint4*>(&sA[row * 256 + ((gc ^ (row & 7)) << 3)]) = pk.q;
    }
    __syncthreads();

    const int lane = tid & 63, wave = tid >> 6;
    const int wr = wave >> 2, wcc = wave & 3;
    const int l15 = lane & 15, l16 = lane >> 4;

    f32x4 acc[4][8];
    #pragma unroll
    for (int mt = 0; mt < 4; ++mt)
        #pragma unroll
        for (int nt = 0; nt < 8; ++nt) acc[mt][nt] = f32x4{0.f, 0.f, 0.f, 0.f};

    #pragma unroll
    for (int ks = 0; ks < 8; ++ks) {
        bf16x8 af[4];
        #pragma unroll
        for (int mt = 0; mt < 4; ++mt) {
            int row = wr * 64 + mt * 16 + l15;
            int g = ks * 4 + l16;
            af[mt] = *reinterpret_cast<const bf16x8*>(&sA[row * 256 + ((g ^ (row & 7)) << 3)]);
        }
        bf16x8 bfr[8];
        #pragma unroll
        for (int nt = 0; nt < 8; ++nt) {
            int col = cb * 512 + wcc * 128 + nt * 16 + l15;
            bfr[nt] = *reinterpret_cast<const bf16x8*>(&Wp1[((size_t)(ks * 4 + l16) * 1024 + col) * 8]);
        }
        #pragma unroll
        for (int mt = 0; mt < 4; ++mt)
            #pragma unroll
            for (int nt = 0; nt < 8; ++nt)
                acc[mt][nt] = __builtin_amdgcn_mfma_f32_16x16x32_bf16(af[mt], bfr[nt], acc[mt][nt], 0, 0, 0);
    }

    // epilogue: paired bf16 (uint) writes into packed layout
    #pragma unroll
    for (int np = 0; np < 4; ++np) {
        int zc0 = wcc * 128 + np * 32 + l15;     // nt = 2*np ; zc1 = zc0 + 16
        float b0 = (cb == 0) ? fc_b[zc0] : 0.f;
        float b1 = (cb == 0) ? fc_b[zc0 + 16] : 0.f;
        int pa = cb * 512 + packAddr8(zc0);      // even; zc0+16 lands at pa+1
        #pragma unroll
        for (int mt = 0; mt < 4; ++mt) {
            #pragma unroll
            for (int j = 0; j < 4; ++j) {
                int row = r0 + wr * 64 + mt * 16 + l16 * 4 + j;
                if (row < N_ATOMS) {
                    unsigned lo = f2bf(acc[mt][2 * np][j] + b0);
                    unsigned hi = f2bf(acc[mt][2 * np + 1][j] + b1);
                    *reinterpret_cast<unsigned*>(&P[(size_t)row * 1024 + pa]) = lo | (hi << 16);
                }
            }
        }
    }
}

// ---------------- Kernel 2: fused bond-GEMM + gather-add + LN1 + gate*core + mean + LN2 + residual
// 512 threads = 8 waves; 4 atoms (48 rows). Wave wc owns 32 gate cols + 32 core cols.
__global__ __launch_bounds__(512, 4) void fused_conv(
    const float* __restrict__ atom, const float* __restrict__ bond,
    const int* __restrict__ nbr, const unsigned short* __restrict__ P,
    const unsigned short* __restrict__ Wp3,
    const float* __restrict__ ln1_g, const float* __restrict__ ln1_b,
    const float* __restrict__ ln2_g, const float* __restrict__ ln2_b,
    float* __restrict__ out)
{
    __shared__ unsigned short sA[48 * 128];              // 12KB bond tile (bf16, swizzled)
    __shared__ float sRed[2][48][9];                     // padded: banks differ across l16 rows
    __shared__ float sMuR[48], sRstd[48];                // LN1 folded stats
    __shared__ float sO[4][256];                         // 4KB per-atom sum of gate*core

    const int tid = threadIdx.x;
    const int i0 = blockIdx.x * 4;                       // 7500 blocks exact
    const int lane = tid & 63, wc = tid >> 6;
    const int l15 = lane & 15, l16 = lane >> 4;

    { float* so = &sO[0][0]; so[tid] = 0.f; so[tid + 512] = 0.f; }

    // ---- 1) neighbor indices FIRST (oldest in vmcnt queue; bond stays in flight when we wait on these)
    int nb[12];
    #pragma unroll
    for (int mt = 0; mt < 3; ++mt)
        #pragma unroll
        for (int j = 0; j < 4; ++j)
            nb[mt * 4 + j] = nbr[i0 * 12 + mt * 16 + l16 * 4 + j];

    // ---- 2) bond loads
    float4 bv[2][2];
    #pragma unroll
    for (int s = 0; s < 2; ++s) {
        int G = tid + s * 512;
        if (G < 768) {
            int row = G >> 4, gc = G & 15;
            const float4* src = reinterpret_cast<const float4*>(bond + (size_t)(i0 * 12 + row) * 128 + gc * 8);
            bv[s][0] = src[0]; bv[s][1] = src[1];
        }
    }

    // ---- 3) P2 gathers (waits only on nb; bond loads remain outstanding) + P1
    uint2 p2q[12];
    #pragma unroll
    for (int k = 0; k < 12; ++k)
        p2q[k] = *reinterpret_cast<const uint2*>(&P[(size_t)nb[k] * 1024 + 512 + wc * 64 + l15 * 4]);
    uint2 p1q[3];
    #pragma unroll
    for (int mt = 0; mt < 3; ++mt) {
        int li = (mt * 16 + l16 * 4) / 12;               // j-quads never cross atoms
        p1q[mt] = *reinterpret_cast<const uint2*>(&P[(size_t)(i0 + li) * 1024 + wc * 64 + l15 * 4]);
    }

    // ---- 4) convert + stage bond tile (waits on bond only; gathers stay in flight)
    #pragma unroll
    for (int s = 0; s < 2; ++s) {
        int G = tid + s * 512;
        if (G < 768) {
            int row = G >> 4, gc = G & 15;
            union { unsigned short u[8]; uint4 q; } pk;
            pk.u[0]=f2bf(bv[s][0].x); pk.u[1]=f2bf(bv[s][0].y); pk.u[2]=f2bf(bv[s][0].z); pk.u[3]=f2bf(bv[s][0].w);
            pk.u[4]=f2bf(bv[s][1].x); pk.u[5]=f2bf(bv[s][1].y); pk.u[6]=f2bf(bv[s][1].z); pk.u[7]=f2bf(bv[s][1].w);
            *reinterpret_cast<uint4*>(&sA[row * 128 + ((gc ^ (row & 7)) << 3)]) = pk.q;
        }
    }
    __syncthreads();

    // ---- GEMM: [48,128(bond)] @ Wp3, wave's cols = 32 gate (nt 0,1) + 32 core (nt 2,3) ----
    f32x4 acc[3][4];
    #pragma unroll
    for (int mt = 0; mt < 3; ++mt)
        #pragma unroll
        for (int nt = 0; nt < 4; ++nt) acc[mt][nt] = f32x4{0.f, 0.f, 0.f, 0.f};

    #pragma unroll
    for (int ks = 0; ks < 4; ++ks) {
        bf16x8 af[3];
        #pragma unroll
        for (int mt = 0; mt < 3; ++mt) {
            int row = mt * 16 + l15;
            int g = ks * 4 + l16;
            af[mt] = *reinterpret_cast<const bf16x8*>(&sA[row * 128 + ((g ^ (row & 7)) << 3)]);
        }
        bf16x8 bfr[4];
        #pragma unroll
        for (int nt = 0; nt < 4; ++nt) {
            int col = (nt < 2) ? (wc * 32 + nt * 16 + l15)
                               : (256 + wc * 32 + (nt - 2) * 16 + l15);
            bfr[nt] = *reinterpret_cast<const bf16x8*>(&Wp3[((size_t)(ks * 4 + l16) * 512 + col) * 8]);
        }
        #pragma unroll
        for (int mt = 0; mt < 3; ++mt)
            #pragma unroll
            for (int nt = 0; nt < 4; ++nt)
                acc[mt][nt] = __builtin_amdgcn_mfma_f32_16x16x32_bf16(af[mt], bfr[nt], acc[mt][nt], 0, 0, 0);
    }

    // ---- pass 1: z = acc + P1 + P2 (from prefetched regs), LN1 partial stats ----
    #pragma unroll
    for (int mt = 0; mt < 3; ++mt) {
        union { uint2 q; unsigned short u[4]; } c1; c1.q = p1q[mt];
        #pragma unroll
        for (int j = 0; j < 4; ++j) {
            const int row = mt * 16 + l16 * 4 + j;
            union { uint2 q; unsigned short u[4]; } c2; c2.q = p2q[mt * 4 + j];
            float s = 0.f, q = 0.f;
            #pragma unroll
            for (int nt = 0; nt < 4; ++nt) {
                float z = acc[mt][nt][j] + bf2f(c1.u[nt]) + bf2f(c2.u[nt]);
                acc[mt][nt][j] = z;
                s += z; q = fmaf(z, z, q);
            }
            #pragma unroll
            for (int msk = 1; msk <= 8; msk <<= 1) {
                s += __shfl_xor(s, msk, 64);
                q += __shfl_xor(q, msk, 64);
            }
            if (l15 == 0) { sRed[0][row][wc] = s; sRed[1][row][wc] = q; }
        }
    }

    // LN1 affine params loaded HERE: latency hides under the barrier + mini-reduce,
    // and they are not live across the GEMM (saves ~8 VGPRs at peak).
    float g1[2], b1[2], gC[2], bC[2];
    #pragma unroll
    for (int nt = 0; nt < 2; ++nt) {
        int a = wc * 32 + nt * 16 + l15;
        g1[nt] = ln1_g[a];       b1[nt] = ln1_b[a];
        gC[nt] = ln1_g[256 + a]; bC[nt] = ln1_b[256 + a];
    }
    __syncthreads();

    // ---- mini-reduce: 48 threads fold 8 wave-partials -> mu*rstd, rstd ----
    if (tid < 48) {
        float s4 = 0.f, q4 = 0.f;
        #pragma unroll
        for (int w = 0; w < 8; ++w) { s4 += sRed[0][tid][w]; q4 += sRed[1][tid][w]; }
        float mu = s4 * (1.f / 512.f);
        float var = q4 * (1.f / 512.f) - mu * mu;
        float rs = __builtin_amdgcn_rsqf(var + 1e-5f);
        sRstd[tid] = rs;
        sMuR[tid] = mu * rs;
    }
    __syncthreads();

    // ---- pass 2: LN1 affine, sigmoid*softplus, accumulate per-atom mean via LDS atomics ----
    #pragma unroll
    for (int mt = 0; mt < 3; ++mt) {
        const int li = (mt * 16 + l16 * 4) / 12;
        float rs[4], mr[4];
        #pragma unroll
        for (int j = 0; j < 4; ++j) {
            int row = mt * 16 + l16 * 4 + j;
            rs[j] = sRstd[row]; mr[j] = sMuR[row];
        }
        #pragma unroll
        for (int nt = 0; nt < 2; ++nt) {
            float tq = 0.f;
            #pragma unroll
            for (int j = 0; j < 4; ++j) {
                float zg = fmaf(acc[mt][nt][j], rs[j], -mr[j]);
                zg = fmaf(zg, g1[nt], b1[nt]);
                float zc = fmaf(acc[mt][nt + 2][j], rs[j], -mr[j]);
                zc = fmaf(zc, gC[nt], bC[nt]);
                float gate = __builtin_amdgcn_rcpf(1.f + __expf(-zg));
                float sp   = fmaxf(zc, 0.f) + __logf(1.f + __expf(-fabsf(zc)));
                tq += gate * sp;
            }
            atomicAdd(&sO[li][wc * 32 + nt * 16 + l15], tq);   // 3 contributors per address
        }
    }
    __syncthreads();

    // ---- mean /12 + LN2 + residual: waves 0..3, one atom each ----
    if (wc < 4) {
        const int gi = i0 + wc;
        float v[4]; float s = 0.f, q = 0.f;
        #pragma unroll
        for (int qd = 0; qd < 4; ++qd) {
            v[qd] = sO[wc][lane + qd * 64] * (1.f / 12.f);
            s += v[qd]; q = fmaf(v[qd], v[qd], q);
        }
        #pragma unroll
        for (int msk = 1; msk <= 32; msk <<= 1) {
            s += __shfl_xor(s, msk, 64);
            q += __shfl_xor(q, msk, 64);
        }
        float mu = s * (1.f / 256.f);
        float var = q * (1.f / 256.f) - mu * mu;
        float rstd = __builtin_amdgcn_rsqf(var + 1e-5f);
        #pragma unroll
        for (int qd = 0; qd < 4; ++qd) {
            int a = lane + qd * 64;
            out[(size_t)gi * 256 + a] = atom[(size_t)gi * 256 + a]
                                      + (v[qd] - mu) * rstd * ln2_g[a] + ln2_b[a];
        }
    }
}

extern "C" void kernel_launch(void* const* d_in, const int* in_sizes, int n_in,
                              void* d_out, int out_size, void* d_ws, size_t ws_size,
                              hipStream_t stream) {
    const float* atom  = (const float*)d_in[0];
    const float* bond  = (const float*)d_in[1];
    const float* fc_w  = (const float*)d_in[2];
    const float* fc_b  = (const float*)d_in[3];
    const float* ln1_g = (const float*)d_in[4];
    const float* ln1_b = (const float*)d_in[5];
    const float* ln2_g = (const float*)d_in[6];
    const float* ln2_b = (const float*)d_in[7];
    const int*   nbr   = (const int*)d_in[8];

    char* ws = (char*)d_ws;
    unsigned short* P   = (unsigned short*)ws;                          // 61,440,000 B
    unsigned short* Wp1 = (unsigned short*)(ws + 61440000);             // 524,288 B
    unsigned short* Wp3 = (unsigned short*)(ws + 61440000 + 524288);    // 131,072 B
    float* outp = (float*)d_out;

    hipLaunchKernelGGL(pack_weights, dim3(1280), dim3(256), 0, stream, fc_w, Wp1, Wp3);
    hipLaunchKernelGGL(gemm_p, dim3(235, 2), dim3(512), 0, stream, atom, fc_b, Wp1, P);
    hipLaunchKernelGGL(fused_conv, dim3(7500), dim3(512), 0, stream,
                       atom, bond, nbr, P, Wp3, ln1_g, ln1_b, ln2_g, ln2_b, outp);
}